// Round 18
// baseline (36.617 us; speedup 1.0000x reference)
//
#include <hip/hip_runtime.h>
#include <hip/hip_bf16.h>

#define B_ 8
#define W_ 128
#define K_ 2048
#define D_ 256
#define WX 144            // padded w-dim: 128 x-cols + E1-col(128) + 15 zero cols
#define NC 256            // K/8 j-chunks

typedef __attribute__((ext_vector_type(8))) short bf16x8;
typedef __attribute__((ext_vector_type(4))) float f32x4;
typedef unsigned int u32;

static __device__ __forceinline__ short f2bf(float f) {
    unsigned int u = __float_as_uint(f);
    unsigned int r = (u + 0x7FFFu + ((u >> 16) & 1u)) >> 16;
    return (short)r;
}

// ---------- k_w2v ----------
__global__ void k_w2v(const float* __restrict__ W_lin, const float* __restrict__ a,
                      float* __restrict__ w2v) {
    int w = blockIdx.x, l = threadIdx.x;
    float4 rv = ((const float4*)(W_lin + (size_t)(W_ + w) * D_))[l];
    float4 av = ((const float4*)a)[l];
    float acc = rv.x * av.x + rv.y * av.y + rv.z * av.z + rv.w * av.w;
    for (int m = 1; m < 64; m <<= 1) acc += __shfl_xor(acc, m);
    if (l == 0) w2v[w] = acc;
}

// ---------- k_pe: heterogeneous grid (1024 blocks x 512 thr) [r17 proven, unchanged]
__global__ __launch_bounds__(512) void k_pe(const float* __restrict__ x,
        const float* __restrict__ w2v, const float* __restrict__ bias,
        short* __restrict__ xbt, short* __restrict__ e2t) {
    __shared__ float sc[696];
    int tid = threadIdx.x;
    int wid = tid >> 6;
    int lane = tid & 63;

    if (blockIdx.x < 512) {
        if (tid < W_) sc[tid] = w2v[tid];          // ws
        __syncthreads();
        int q = tid & 31, cw = tid >> 5;           // cw 0..15, 8 w each
        int bk0 = blockIdx.x * 32;
        int b = bk0 >> 11;
        int k = (bk0 & (K_ - 1)) + q;
        const float* xp = x + ((size_t)b * W_ + cw * 8) * K_ + k;
        float xv[8];
        float acc = 0.f;
#pragma unroll
        for (int w = 0; w < 8; ++w) {
            xv[w] = xp[(size_t)w * K_];
            acc += xv[w] * sc[cw * 8 + w];
        }
        sc[128 + cw * 33 + q] = acc;               // red[16][33]
        __syncthreads();
        if (tid < 32) {
            float s = 0.f;
#pragma unroll
            for (int cc = 0; cc < 16; ++cc) s += sc[128 + cc * 33 + tid];
            sc[656 + tid] = __expf(s);             // e1s; |u2| small, shift-invariant
        }
        __syncthreads();
        float e1q = sc[656 + q];
        short* xo = xbt + (((size_t)b * NC + (k >> 3)) * WX + cw * 8) * 8 + (k & 7);
#pragma unroll
        for (int w = 0; w < 8; ++w) xo[w * 8] = f2bf(xv[w] * e1q);
        if (tid < 32) {   // E1 column (w=128)
            int kk = (bk0 & (K_ - 1)) + tid;
            xbt[(((size_t)b * NC + (kk >> 3)) * WX + 128) * 8 + (kk & 7)] = f2bf(sc[656 + tid]);
        }
        if (tid >= 64 && tid < 124) {   // zero cols 129..143
            int id = tid - 64;
            int cl = id / 15, wz = 129 + id % 15;
            int c = ((bk0 & (K_ - 1)) >> 3) + cl;
            bf16x8 z = {0, 0, 0, 0, 0, 0, 0, 0};
            *(bf16x8*)(xbt + (((size_t)b * NC + c) * WX + wz) * 8) = z;
        }
    } else {
        // ---- e2 single-pass ----
        int i0e = (int)(blockIdx.x - 512) * 4;
        int il = tid & 3, cg = tid >> 2;           // cg 0..127
        const float4* brow = (const float4*)(bias + (size_t)(i0e + il) * K_);
        float4 v0 = brow[cg * 4 + 0];
        float4 v1 = brow[cg * 4 + 1];
        float4 v2 = brow[cg * 4 + 2];
        float4 v3 = brow[cg * 4 + 3];
        float m = fmaxf(fmaxf(fmaxf(v0.x, v0.y), fmaxf(v0.z, v0.w)),
                        fmaxf(fmaxf(v1.x, v1.y), fmaxf(v1.z, v1.w)));
        m = fmaxf(m, fmaxf(fmaxf(fmaxf(v2.x, v2.y), fmaxf(v2.z, v2.w)),
                           fmaxf(fmaxf(v3.x, v3.y), fmaxf(v3.z, v3.w))));
#pragma unroll
        for (int mm = 4; mm < 64; mm <<= 1) m = fmaxf(m, __shfl_xor(m, mm));
        if (lane < 4) sc[wid * 4 + lane] = m;
        __syncthreads();
        float mb = sc[il];
#pragma unroll
        for (int w = 1; w < 8; ++w) mb = fmaxf(mb, sc[w * 4 + il]);
        bf16x8 o0, o1;
        o0[0] = f2bf(__expf(v0.x - mb)); o0[1] = f2bf(__expf(v0.y - mb));
        o0[2] = f2bf(__expf(v0.z - mb)); o0[3] = f2bf(__expf(v0.w - mb));
        o0[4] = f2bf(__expf(v1.x - mb)); o0[5] = f2bf(__expf(v1.y - mb));
        o0[6] = f2bf(__expf(v1.z - mb)); o0[7] = f2bf(__expf(v1.w - mb));
        o1[0] = f2bf(__expf(v2.x - mb)); o1[1] = f2bf(__expf(v2.y - mb));
        o1[2] = f2bf(__expf(v2.z - mb)); o1[3] = f2bf(__expf(v2.w - mb));
        o1[4] = f2bf(__expf(v3.x - mb)); o1[5] = f2bf(__expf(v3.y - mb));
        o1[6] = f2bf(__expf(v3.z - mb)); o1[7] = f2bf(__expf(v3.w - mb));
        int i = i0e + il;
        *(bf16x8*)(e2t + ((size_t)(cg * 2) * K_ + i) * 8)     = o0;
        *(bf16x8*)(e2t + ((size_t)(cg * 2 + 1) * K_ + i) * 8) = o1;
    }
}

// ---------- k_gemm: R=32 per wave — 9 ds_read feed 18 MFMA (halves LDS reads)
// grid 256 x 512 thr: b = blk&7 (XCD-pinned), i0 = (blk>>3)*64 (64 rows).
// 8 waves = 2 m-pairs (mp: 2 A-frags = 32 rows) x 4 jq (512 j, 16 K-steps).
// Ring: 4 buffers x 9KB per jq (147KB), counted vmcnt, raw barriers (r16 T3/T4).
#define MF(a_, b_, c_) __builtin_amdgcn_mfma_f32_16x16x32_bf16(a_, b_, c_, 0, 0, 0)

#define GLLDS(gsrc, ldst) __builtin_amdgcn_global_load_lds(                      \
    (const u32 __attribute__((address_space(1)))*)(const void*)(gsrc),           \
    (u32 __attribute__((address_space(3)))*)(void*)(ldst), 16, 0, 0)

#define WAITV(n_) asm volatile("s_waitcnt vmcnt(" #n_ ")" ::: "memory")
#define BARR __builtin_amdgcn_s_barrier()

__global__ __launch_bounds__(512, 2) void k_gemm(const short* __restrict__ e2t,
        const short* __restrict__ xbt, float* __restrict__ out) {
    __shared__ __align__(16) char Bb[147456];   // [jq][4 ring][9216]; aliased for reduce
    int blk  = blockIdx.x;
    int b    = blk & 7;                  // XCD round-robin -> same b per XCD
    int i0   = (blk >> 3) * 64;
    int tid  = threadIdx.x;
    int wid  = tid >> 6;                 // 0..7
    int lane = tid & 63;
    int il   = lane & 15;
    int kg   = lane >> 4;
    int mp   = wid & 1;                  // m-pair: rows i0 + mp*32 .. +31 (2 frags)
    int jq   = wid >> 1;                 // j-quarter: 512 j, 16 K-steps

    int i0r = i0 + mp * 32;
    const short* eA = e2t + (((size_t)(jq * 64 + kg)) * K_ + i0r + il) * 8;
    size_t xbase = ((size_t)b * NC + jq * 64 + kg) * WX + il;
    char* jbuf = Bb + jq * 36864;

#define STG(s_) do {                                                             \
    const short* _g = xbt + (xbase + (size_t)(s_) * 4 * WX) * 8;                 \
    char* _d = jbuf + ((s_) & 3) * 9216;                                         \
    for (int f = mp; f < 9; f += 2)                                              \
        GLLDS(_g + f * 128, _d + f * 1024);                                      \
} while (0)

// A-frag ring: slot sl holds rows (il, il+16) of 32-row pair for step s
#define FAix(sl_, s_) do {                                                       \
    const short* _e = eA + (size_t)(s_) * 4 * K_ * 8;                            \
    ArA##sl_ = *(const bf16x8*)(_e);                                             \
    ArB##sl_ = *(const bf16x8*)(_e + 128);                                       \
} while (0)

    f32x4 qa0{0,0,0,0}, qa1{0,0,0,0}, qa2{0,0,0,0}, qa3{0,0,0,0}, qa4{0,0,0,0},
          qa5{0,0,0,0}, qa6{0,0,0,0}, qa7{0,0,0,0}, qa8{0,0,0,0};
    f32x4 qb0{0,0,0,0}, qb1{0,0,0,0}, qb2{0,0,0,0}, qb3{0,0,0,0}, qb4{0,0,0,0},
          qb5{0,0,0,0}, qb6{0,0,0,0}, qb7{0,0,0,0}, qb8{0,0,0,0};

#define CONS(s_, sl_) do {                                                       \
    const char* _bp = jbuf + ((s_) & 3) * 9216;                                  \
    bf16x8 b0 = *(const bf16x8*)(_bp +    0 + lane * 16);                        \
    bf16x8 b1 = *(const bf16x8*)(_bp + 1024 + lane * 16);                        \
    bf16x8 b2 = *(const bf16x8*)(_bp + 2048 + lane * 16);                        \
    bf16x8 b3 = *(const bf16x8*)(_bp + 3072 + lane * 16);                        \
    bf16x8 b4 = *(const bf16x8*)(_bp + 4096 + lane * 16);                        \
    bf16x8 b5 = *(const bf16x8*)(_bp + 5120 + lane * 16);                        \
    bf16x8 b6 = *(const bf16x8*)(_bp + 6144 + lane * 16);                        \
    bf16x8 b7 = *(const bf16x8*)(_bp + 7168 + lane * 16);                        \
    bf16x8 b8 = *(const bf16x8*)(_bp + 8192 + lane * 16);                        \
    __builtin_amdgcn_s_setprio(1);                                               \
    qa0 = MF(ArA##sl_, b0, qa0); qb0 = MF(ArB##sl_, b0, qb0);                    \
    qa1 = MF(ArA##sl_, b1, qa1); qb1 = MF(ArB##sl_, b1, qb1);                    \
    qa2 = MF(ArA##sl_, b2, qa2); qb2 = MF(ArB##sl_, b2, qb2);                    \
    qa3 = MF(ArA##sl_, b3, qa3); qb3 = MF(ArB##sl_, b3, qb3);                    \
    qa4 = MF(ArA##sl_, b4, qa4); qb4 = MF(ArB##sl_, b4, qb4);                    \
    qa5 = MF(ArA##sl_, b5, qa5); qb5 = MF(ArB##sl_, b5, qb5);                    \
    qa6 = MF(ArA##sl_, b6, qa6); qb6 = MF(ArB##sl_, b6, qb6);                    \
    qa7 = MF(ArA##sl_, b7, qa7); qb7 = MF(ArB##sl_, b7, qb7);                    \
    qa8 = MF(ArA##sl_, b8, qa8); qb8 = MF(ArB##sl_, b8, qb8);                    \
    __builtin_amdgcn_s_setprio(0);                                               \
} while (0)

// in-loop allowed outstanding = stages s+1,s+2: mp0 (2A+5B)x2=14, mp1 (2A+4B)x2=12
#define STEP(s_, sl_, s2_, sl2_) do {                                            \
    FAix(sl2_, s2_); STG(s2_);                                                   \
    if (mp == 0) WAITV(14); else WAITV(12);                                      \
    BARR;                                                                        \
    CONS(s_, sl_);                                                               \
} while (0)

    bf16x8 ArA0, ArA1, ArA2, ArA3, ArB0, ArB1, ArB2, ArB3;
    FAix(0, 0); STG(0);
    FAix(1, 1); STG(1);

    STEP(0, 0, 2, 2);   STEP(1, 1, 3, 3);
    STEP(2, 2, 4, 0);   STEP(3, 3, 5, 1);
    STEP(4, 0, 6, 2);   STEP(5, 1, 7, 3);
    STEP(6, 2, 8, 0);   STEP(7, 3, 9, 1);
    STEP(8, 0, 10, 2);  STEP(9, 1, 11, 3);
    STEP(10, 2, 12, 0); STEP(11, 3, 13, 1);
    STEP(12, 0, 14, 2); STEP(13, 1, 15, 3);
    if (mp == 0) WAITV(7); else WAITV(6);
    BARR;
    CONS(14, 2);
    WAITV(0);
    BARR;
    CONS(15, 3);

    __syncthreads();                     // full drain before LDS re-use

    // two parallel jq-trees (one per mp): 4 -> 2 -> 1, then jq0 stores
    f32x4* R = (f32x4*)Bb;
#define DUMPQ(slot_) do {                                                        \
    f32x4* _r = R + (size_t)(slot_) * 18 * 64 + lane;                            \
    _r[0*64]=qa0; _r[1*64]=qa1; _r[2*64]=qa2; _r[3*64]=qa3; _r[4*64]=qa4;        \
    _r[5*64]=qa5; _r[6*64]=qa6; _r[7*64]=qa7; _r[8*64]=qa8;                      \
    _r[9*64]=qb0; _r[10*64]=qb1; _r[11*64]=qb2; _r[12*64]=qb3; _r[13*64]=qb4;    \
    _r[14*64]=qb5; _r[15*64]=qb6; _r[16*64]=qb7; _r[17*64]=qb8; } while (0)
#define GATHQ(slot_) do {                                                        \
    f32x4* _r = R + (size_t)(slot_) * 18 * 64 + lane;                            \
    qa0+=_r[0*64]; qa1+=_r[1*64]; qa2+=_r[2*64]; qa3+=_r[3*64]; qa4+=_r[4*64];   \
    qa5+=_r[5*64]; qa6+=_r[6*64]; qa7+=_r[7*64]; qa8+=_r[8*64];                  \
    qb0+=_r[9*64]; qb1+=_r[10*64]; qb2+=_r[11*64]; qb3+=_r[12*64];               \
    qb4+=_r[13*64]; qb5+=_r[14*64]; qb6+=_r[15*64]; qb7+=_r[16*64];              \
    qb8+=_r[17*64]; } while (0)

    if (jq >= 2) DUMPQ((jq - 2) + 2 * mp);
    __syncthreads();
    if (jq < 2) GATHQ(jq + 2 * mp);
    __syncthreads();
    if (jq == 1) DUMPQ(mp);
    __syncthreads();
    if (jq == 0) {
        GATHQ(mp);
        // l for rows kg*4+r: qa8/qb8[r] at lane kg*16 (w=128 column)
        float lA0 = 1.f / __shfl(qa8[0], kg * 16);
        float lA1 = 1.f / __shfl(qa8[1], kg * 16);
        float lA2 = 1.f / __shfl(qa8[2], kg * 16);
        float lA3 = 1.f / __shfl(qa8[3], kg * 16);
        float lB0 = 1.f / __shfl(qb8[0], kg * 16);
        float lB1 = 1.f / __shfl(qb8[1], kg * 16);
        float lB2 = 1.f / __shfl(qb8[2], kg * 16);
        float lB3 = 1.f / __shfl(qb8[3], kg * 16);
        float* obA = out + (size_t)b * W_ * K_ + i0r + kg * 4;
        float* obB = obA + 16;
#define STQ(ob_, n_, q_, l0_, l1_, l2_, l3_) do {                                \
        float4 o;                                                                \
        o.x = 1.f / (1.f + __expf(-q_[0] * l0_));                                \
        o.y = 1.f / (1.f + __expf(-q_[1] * l1_));                                \
        o.z = 1.f / (1.f + __expf(-q_[2] * l2_));                                \
        o.w = 1.f / (1.f + __expf(-q_[3] * l3_));                                \
        *(float4*)(ob_ + (size_t)((n_) * 16 + il) * K_) = o; } while (0)
        STQ(obA, 0, qa0, lA0, lA1, lA2, lA3); STQ(obB, 0, qb0, lB0, lB1, lB2, lB3);
        STQ(obA, 1, qa1, lA0, lA1, lA2, lA3); STQ(obB, 1, qb1, lB0, lB1, lB2, lB3);
        STQ(obA, 2, qa2, lA0, lA1, lA2, lA3); STQ(obB, 2, qb2, lB0, lB1, lB2, lB3);
        STQ(obA, 3, qa3, lA0, lA1, lA2, lA3); STQ(obB, 3, qb3, lB0, lB1, lB2, lB3);
        STQ(obA, 4, qa4, lA0, lA1, lA2, lA3); STQ(obB, 4, qb4, lB0, lB1, lB2, lB3);
        STQ(obA, 5, qa5, lA0, lA1, lA2, lA3); STQ(obB, 5, qb5, lB0, lB1, lB2, lB3);
        STQ(obA, 6, qa6, lA0, lA1, lA2, lA3); STQ(obB, 6, qb6, lB0, lB1, lB2, lB3);
        STQ(obA, 7, qa7, lA0, lA1, lA2, lA3); STQ(obB, 7, qb7, lB0, lB1, lB2, lB3);
#undef STQ
    }
}

extern "C" void kernel_launch(void* const* d_in, const int* in_sizes, int n_in,
                              void* d_out, int out_size, void* d_ws, size_t ws_size,
                              hipStream_t stream) {
    const float* x     = (const float*)d_in[0];
    const float* W_lin = (const float*)d_in[1];
    // d_in[2] = b_lin: constant along softmax axis -> cancels, unused
    const float* a     = (const float*)d_in[3];
    const float* bias  = (const float*)d_in[4];
    float* out = (float*)d_out;

    float* w2v = (float*)d_ws;                    // 128 f32
    short* xbt = (short*)(w2v + 128);             // 8*256*144*8 bf16 = 4.72 MB
    short* e2t = xbt + (size_t)B_ * NC * WX * 8;  // 256*2048*8 bf16 = 8 MB

    k_w2v <<<128, 64, 0, stream>>>(W_lin, a, w2v);
    k_pe  <<<1024, 512, 0, stream>>>(x, w2v, bias, xbt, e2t);
    k_gemm<<<256, 512, 0, stream>>>(e2t, xbt, out);
}

// Round 19
// 33.383 us; speedup vs baseline: 1.0969x; 1.0969x over previous
//
#include <hip/hip_runtime.h>
#include <hip/hip_bf16.h>

#define B_ 8
#define W_ 128
#define K_ 2048
#define D_ 256
#define WX 144            // padded w-dim: 128 x-cols + E1-col(128) + 15 zero cols
#define NC 256            // K/8 j-chunks

typedef __attribute__((ext_vector_type(8))) short bf16x8;
typedef __attribute__((ext_vector_type(4))) float f32x4;
typedef unsigned int u32;

static __device__ __forceinline__ short f2bf(float f) {
    unsigned int u = __float_as_uint(f);
    unsigned int r = (u + 0x7FFFu + ((u >> 16) & 1u)) >> 16;
    return (short)r;
}

// ---------- k_w2v ----------
__global__ void k_w2v(const float* __restrict__ W_lin, const float* __restrict__ a,
                      float* __restrict__ w2v) {
    int w = blockIdx.x, l = threadIdx.x;
    float4 rv = ((const float4*)(W_lin + (size_t)(W_ + w) * D_))[l];
    float4 av = ((const float4*)a)[l];
    float acc = rv.x * av.x + rv.y * av.y + rv.z * av.z + rv.w * av.w;
    for (int m = 1; m < 64; m <<= 1) acc += __shfl_xor(acc, m);
    if (l == 0) w2v[w] = acc;
}

// ---------- k_pe: heterogeneous grid (1024 blocks x 512 thr)
// blocks 0..511  : prep — now with LDS-transposed COALESCED xbt stores
// blocks 512..1023: e2 single-pass (r17 proven)
__global__ __launch_bounds__(512) void k_pe(const float* __restrict__ x,
        const float* __restrict__ w2v, const float* __restrict__ bias,
        short* __restrict__ xbt, short* __restrict__ e2t) {
    __shared__ float sc[696];
    __shared__ __align__(16) short ldt[128][4][8];   // [w][c][e] transpose tile, 8 KB
    int tid = threadIdx.x;
    int wid = tid >> 6;
    int lane = tid & 63;

    if (blockIdx.x < 512) {
        if (tid < W_) sc[tid] = w2v[tid];          // ws
        __syncthreads();
        int q = tid & 31, cw = tid >> 5;           // cw 0..15, 8 w each
        int bk0 = blockIdx.x * 32;
        int b = bk0 >> 11;
        int k = (bk0 & (K_ - 1)) + q;
        int c0 = (bk0 & (K_ - 1)) >> 3;
        const float* xp = x + ((size_t)b * W_ + cw * 8) * K_ + k;
        float xv[8];
        float acc = 0.f;
#pragma unroll
        for (int w = 0; w < 8; ++w) {
            xv[w] = xp[(size_t)w * K_];
            acc += xv[w] * sc[cw * 8 + w];
        }
        sc[128 + cw * 33 + q] = acc;               // red[16][33]
        __syncthreads();
        if (tid < 32) {
            float s = 0.f;
#pragma unroll
            for (int cc = 0; cc < 16; ++cc) s += sc[128 + cc * 33 + tid];
            sc[656 + tid] = __expf(s);             // e1s; |u2| small, shift-invariant
        }
        __syncthreads();
        float e1q = sc[656 + q];
        // stage scaled bf16 into transpose tile: [w][c=q>>3][e=q&7]
#pragma unroll
        for (int w = 0; w < 8; ++w)
            ldt[cw * 8 + w][q >> 3][q & 7] = f2bf(xv[w] * e1q);
        if (tid < 32) {   // E1 column (w=128)
            int kk = (bk0 & (K_ - 1)) + tid;
            xbt[(((size_t)b * NC + (kk >> 3)) * WX + 128) * 8 + (kk & 7)] = f2bf(sc[656 + tid]);
        }
        if (tid >= 64 && tid < 124) {   // zero cols 129..143
            int id = tid - 64;
            int cl = id / 15, wz = 129 + id % 15;
            int c = c0 + cl;
            bf16x8 z = {0, 0, 0, 0, 0, 0, 0, 0};
            *(bf16x8*)(xbt + (((size_t)b * NC + c) * WX + wz) * 8) = z;
        }
        __syncthreads();
        // coalesced write-out: thread t -> (c = t&3, w = t>>2); 16B store, 256B runs
        {
            int c = tid & 3, w = tid >> 2;
            bf16x8 v = *(const bf16x8*)&ldt[w][c][0];
            *(bf16x8*)(xbt + (((size_t)b * NC + c0 + c) * WX + w) * 8) = v;
        }
    } else {
        // ---- e2 single-pass ----
        int i0e = (int)(blockIdx.x - 512) * 4;
        int il = tid & 3, cg = tid >> 2;           // cg 0..127
        const float4* brow = (const float4*)(bias + (size_t)(i0e + il) * K_);
        float4 v0 = brow[cg * 4 + 0];
        float4 v1 = brow[cg * 4 + 1];
        float4 v2 = brow[cg * 4 + 2];
        float4 v3 = brow[cg * 4 + 3];
        float m = fmaxf(fmaxf(fmaxf(v0.x, v0.y), fmaxf(v0.z, v0.w)),
                        fmaxf(fmaxf(v1.x, v1.y), fmaxf(v1.z, v1.w)));
        m = fmaxf(m, fmaxf(fmaxf(fmaxf(v2.x, v2.y), fmaxf(v2.z, v2.w)),
                           fmaxf(fmaxf(v3.x, v3.y), fmaxf(v3.z, v3.w))));
#pragma unroll
        for (int mm = 4; mm < 64; mm <<= 1) m = fmaxf(m, __shfl_xor(m, mm));
        if (lane < 4) sc[wid * 4 + lane] = m;
        __syncthreads();
        float mb = sc[il];
#pragma unroll
        for (int w = 1; w < 8; ++w) mb = fmaxf(mb, sc[w * 4 + il]);
        bf16x8 o0, o1;
        o0[0] = f2bf(__expf(v0.x - mb)); o0[1] = f2bf(__expf(v0.y - mb));
        o0[2] = f2bf(__expf(v0.z - mb)); o0[3] = f2bf(__expf(v0.w - mb));
        o0[4] = f2bf(__expf(v1.x - mb)); o0[5] = f2bf(__expf(v1.y - mb));
        o0[6] = f2bf(__expf(v1.z - mb)); o0[7] = f2bf(__expf(v1.w - mb));
        o1[0] = f2bf(__expf(v2.x - mb)); o1[1] = f2bf(__expf(v2.y - mb));
        o1[2] = f2bf(__expf(v2.z - mb)); o1[3] = f2bf(__expf(v2.w - mb));
        o1[4] = f2bf(__expf(v3.x - mb)); o1[5] = f2bf(__expf(v3.y - mb));
        o1[6] = f2bf(__expf(v3.z - mb)); o1[7] = f2bf(__expf(v3.w - mb));
        int i = i0e + il;
        *(bf16x8*)(e2t + ((size_t)(cg * 2) * K_ + i) * 8)     = o0;
        *(bf16x8*)(e2t + ((size_t)(cg * 2 + 1) * K_ + i) * 8) = o1;
    }
}

// ---------- k_gemm: r16 PROVEN version (LDS-staged B, 4-deep ring, counted vmcnt,
// raw barriers, setprio) — byte-identical revert.
#define MF(a_, b_, c_) __builtin_amdgcn_mfma_f32_16x16x32_bf16(a_, b_, c_, 0, 0, 0)

#define GLLDS(gsrc, ldst) __builtin_amdgcn_global_load_lds(                      \
    (const u32 __attribute__((address_space(1)))*)(const void*)(gsrc),           \
    (u32 __attribute__((address_space(3)))*)(void*)(ldst), 16, 0, 0)

#define WAITV(n_) asm volatile("s_waitcnt vmcnt(" #n_ ")" ::: "memory")
#define BARR __builtin_amdgcn_s_barrier()

__global__ __launch_bounds__(1024, 4) void k_gemm(const short* __restrict__ e2t,
        const short* __restrict__ xbt, float* __restrict__ out) {
    __shared__ __align__(16) char Bb[147456];   // [jq][4 ring][9216]; aliased for reduce
    int blk  = blockIdx.x;
    int b    = blk & 7;                  // XCD round-robin -> same b per XCD
    int i0   = (blk >> 3) * 64;
    int tid  = threadIdx.x;
    int wid  = tid >> 6;
    int lane = tid & 63;
    int il   = lane & 15;
    int kg   = lane >> 4;
    int m    = wid & 3;                  // m-tile: rows i0 + m*16 ..
    int jq   = wid >> 2;                 // j-quarter: 512 j, 16 K-steps

    int i0r = i0 + m * 16;
    const short* eA = e2t + (((size_t)(jq * 64 + kg)) * K_ + i0r + il) * 8;
    size_t xbase = ((size_t)b * NC + jq * 64 + kg) * WX + il;
    char* jbuf = Bb + jq * 36864;

#define STG(s_) do {                                                             \
    const short* _g = xbt + (xbase + (size_t)(s_) * 4 * WX) * 8;                 \
    char* _d = jbuf + ((s_) & 3) * 9216;                                         \
    for (int f = m; f < 9; f += 4)                                               \
        GLLDS(_g + f * 128, _d + f * 1024);                                      \
} while (0)

#define FAix(sl_, s_) Ar##sl_ = *(const bf16x8*)(eA + (size_t)(s_) * 4 * K_ * 8)

    f32x4 q0{0,0,0,0}, q1{0,0,0,0}, q2{0,0,0,0}, q3{0,0,0,0}, q4{0,0,0,0},
          q5{0,0,0,0}, q6{0,0,0,0}, q7{0,0,0,0}, q8{0,0,0,0};

#define CONS(s_, sl_) do {                                                       \
    const char* _bp = jbuf + ((s_) & 3) * 9216;                                  \
    bf16x8 b0 = *(const bf16x8*)(_bp +    0 + lane * 16);                        \
    bf16x8 b1 = *(const bf16x8*)(_bp + 1024 + lane * 16);                        \
    bf16x8 b2 = *(const bf16x8*)(_bp + 2048 + lane * 16);                        \
    bf16x8 b3 = *(const bf16x8*)(_bp + 3072 + lane * 16);                        \
    bf16x8 b4 = *(const bf16x8*)(_bp + 4096 + lane * 16);                        \
    bf16x8 b5 = *(const bf16x8*)(_bp + 5120 + lane * 16);                        \
    bf16x8 b6 = *(const bf16x8*)(_bp + 6144 + lane * 16);                        \
    bf16x8 b7 = *(const bf16x8*)(_bp + 7168 + lane * 16);                        \
    bf16x8 b8 = *(const bf16x8*)(_bp + 8192 + lane * 16);                        \
    __builtin_amdgcn_s_setprio(1);                                               \
    q0 = MF(Ar##sl_, b0, q0); q1 = MF(Ar##sl_, b1, q1); q2 = MF(Ar##sl_, b2, q2);\
    q3 = MF(Ar##sl_, b3, q3); q4 = MF(Ar##sl_, b4, q4); q5 = MF(Ar##sl_, b5, q5);\
    q6 = MF(Ar##sl_, b6, q6); q7 = MF(Ar##sl_, b7, q7); q8 = MF(Ar##sl_, b8, q8);\
    __builtin_amdgcn_s_setprio(0);                                               \
} while (0)

#define STEP(s_, sl_, s2_, sl2_) do {                                            \
    FAix(sl2_, s2_); STG(s2_);                                                   \
    if (m == 0) WAITV(8); else WAITV(6);                                         \
    BARR;                                                                        \
    CONS(s_, sl_);                                                               \
} while (0)

    bf16x8 Ar0, Ar1, Ar2, Ar3;
    FAix(0, 0); STG(0);
    FAix(1, 1); STG(1);

    STEP(0, 0, 2, 2);   STEP(1, 1, 3, 3);
    STEP(2, 2, 4, 0);   STEP(3, 3, 5, 1);
    STEP(4, 0, 6, 2);   STEP(5, 1, 7, 3);
    STEP(6, 2, 8, 0);   STEP(7, 3, 9, 1);
    STEP(8, 0, 10, 2);  STEP(9, 1, 11, 3);
    STEP(10, 2, 12, 0); STEP(11, 3, 13, 1);
    STEP(12, 0, 14, 2); STEP(13, 1, 15, 3);
    if (m == 0) WAITV(4); else WAITV(3);
    BARR;
    CONS(14, 2);
    WAITV(0);
    BARR;
    CONS(15, 3);

    __syncthreads();

    f32x4* R = (f32x4*)Bb;
#define DUMPQ(base_) do {                                                        \
    f32x4* _r = R + ((base_) + m * 9) * 64 + lane;                               \
    _r[0*64] = q0; _r[1*64] = q1; _r[2*64] = q2; _r[3*64] = q3; _r[4*64] = q4;   \
    _r[5*64] = q5; _r[6*64] = q6; _r[7*64] = q7; _r[8*64] = q8; } while (0)
#define GATHQ(base_) do {                                                        \
    f32x4* _r = R + ((base_) + m * 9) * 64 + lane;                               \
    q0 += _r[0*64]; q1 += _r[1*64]; q2 += _r[2*64]; q3 += _r[3*64];              \
    q4 += _r[4*64]; q5 += _r[5*64]; q6 += _r[6*64]; q7 += _r[7*64];              \
    q8 += _r[8*64]; } while (0)

    if (jq >= 2) DUMPQ((jq - 2) * 36);
    __syncthreads();
    if (jq < 2) GATHQ(jq * 36);
    __syncthreads();
    if (jq == 1) DUMPQ(0);
    __syncthreads();
    if (jq == 0) {
        GATHQ(0);
        float linv0 = 1.f / __shfl(q8[0], kg * 16);
        float linv1 = 1.f / __shfl(q8[1], kg * 16);
        float linv2 = 1.f / __shfl(q8[2], kg * 16);
        float linv3 = 1.f / __shfl(q8[3], kg * 16);
        float* ob = out + (size_t)b * W_ * K_ + i0r + kg * 4;
#define STQ(n_, q_) do {                                                         \
        float4 o;                                                                \
        o.x = 1.f / (1.f + __expf(-q_[0] * linv0));                              \
        o.y = 1.f / (1.f + __expf(-q_[1] * linv1));                              \
        o.z = 1.f / (1.f + __expf(-q_[2] * linv2));                              \
        o.w = 1.f / (1.f + __expf(-q_[3] * linv3));                              \
        *(float4*)(ob + (size_t)((n_) * 16 + il) * K_) = o; } while (0)
        STQ(0, q0); STQ(1, q1); STQ(2, q2); STQ(3, q3);
        STQ(4, q4); STQ(5, q5); STQ(6, q6); STQ(7, q7);
#undef STQ
    }
}

extern "C" void kernel_launch(void* const* d_in, const int* in_sizes, int n_in,
                              void* d_out, int out_size, void* d_ws, size_t ws_size,
                              hipStream_t stream) {
    const float* x     = (const float*)d_in[0];
    const float* W_lin = (const float*)d_in[1];
    // d_in[2] = b_lin: constant along softmax axis -> cancels, unused
    const float* a     = (const float*)d_in[3];
    const float* bias  = (const float*)d_in[4];
    float* out = (float*)d_out;

    float* w2v = (float*)d_ws;                    // 128 f32
    short* xbt = (short*)(w2v + 128);             // 8*256*144*8 bf16 = 4.72 MB
    short* e2t = xbt + (size_t)B_ * NC * WX * 8;  // 256*2048*8 bf16 = 8 MB

    k_w2v <<<128, 64, 0, stream>>>(W_lin, a, w2v);
    k_pe  <<<1024, 512, 0, stream>>>(x, w2v, bias, xbt, e2t);
    k_gemm<<<256, 1024, 0, stream>>>(e2t, xbt, out);
}